// Round 1
// baseline (385.223 us; speedup 1.0000x reference)
//
#include <hip/hip_runtime.h>

#define T_STEPS 1024
#define B_DIM   128
#define D_DIM   256
#define H_DIM   256
#define DH      512   // D + H

// fast device math: v_exp/v_rcp/v_sin based, ~1-ulp each; recurrence is
// contractive (f = sigmoid(sin(x)) in [0.27, 0.73]) so errors do not grow.
__device__ __forceinline__ float fsigmoid(float x) {
    float e = __expf(-x);
    return __builtin_amdgcn_rcpf(1.0f + e);
}
__device__ __forceinline__ float ftanh_(float x) {
    float e = __expf(2.0f * x);
    return 1.0f - 2.0f * __builtin_amdgcn_rcpf(e + 1.0f);
}

__device__ __forceinline__ float wave_sum(float v) {
#pragma unroll
    for (int off = 32; off > 0; off >>= 1) v += __shfl_xor(v, off, 64);
    return v;
}

// whp[k] = sum_h W[k, 256+h]   (4 waves, one per k)
__global__ __launch_bounds__(256) void k_prep(const float* __restrict__ W,
                                              float* __restrict__ whp) {
    const int k = threadIdx.x >> 6;
    const int lane = threadIdx.x & 63;
    float4 v = ((const float4*)(W + k * DH + D_DIM))[lane];
    float s = v.x + v.y + v.z + v.w;
    s = wave_sum(s);
    if (lane == 0) whp[k] = s;
}

// xdot[row][k] = x[row,:] . W[k,:256] + b[k]   — wave per row, grid-stride
__global__ __launch_bounds__(256) void k_xdot(const float* __restrict__ x,
                                              const float* __restrict__ W,
                                              const float* __restrict__ bias,
                                              float* __restrict__ xdot) {
    const int lane = threadIdx.x & 63;
    const int wid = blockIdx.x * (blockDim.x >> 6) + (threadIdx.x >> 6);
    const int nw = (gridDim.x * blockDim.x) >> 6;
    const int nrows = T_STEPS * B_DIM;

    // per-lane W fragments (first 256 columns of each of the 4 rows)
    float4 wk0 = ((const float4*)(W + 0 * DH))[lane];
    float4 wk1 = ((const float4*)(W + 1 * DH))[lane];
    float4 wk2 = ((const float4*)(W + 2 * DH))[lane];
    float4 wk3 = ((const float4*)(W + 3 * DH))[lane];
    const float b0 = bias[0], b1 = bias[1], b2 = bias[2], b3 = bias[3];

    const float4* xv4 = (const float4*)x;  // 64 float4 per row

    int row = wid;
    if (row >= nrows) return;
    float4 xv = xv4[row * 64 + lane];
    for (; row < nrows; row += nw) {
        float4 cur = xv;
        int nrow = row + nw;
        if (nrow < nrows) xv = xv4[nrow * 64 + lane];  // prefetch next row

        float p0 = fmaf(cur.x, wk0.x, fmaf(cur.y, wk0.y, fmaf(cur.z, wk0.z, cur.w * wk0.w)));
        float p1 = fmaf(cur.x, wk1.x, fmaf(cur.y, wk1.y, fmaf(cur.z, wk1.z, cur.w * wk1.w)));
        float p2 = fmaf(cur.x, wk2.x, fmaf(cur.y, wk2.y, fmaf(cur.z, wk2.z, cur.w * wk2.w)));
        float p3 = fmaf(cur.x, wk3.x, fmaf(cur.y, wk3.y, fmaf(cur.z, wk3.z, cur.w * wk3.w)));
        p0 = wave_sum(p0);
        p1 = wave_sum(p1);
        p2 = wave_sum(p2);
        p3 = wave_sum(p3);
        if (lane == 0) {
            float4 r;
            r.x = p0 + b0; r.y = p1 + b1; r.z = p2 + b2; r.w = p3 + b3;
            ((float4*)xdot)[row] = r;
        }
    }
}

// sequential scan: 128 independent chains (one per batch element)
__global__ __launch_bounds__(128) void k_scan(const float* __restrict__ xdot,
                                              const float* __restrict__ whp,
                                              float* __restrict__ hseq,
                                              float* __restrict__ cfin) {
    const int b = threadIdx.x;  // 0..127
    const float w0 = whp[0], w1 = whp[1], w2 = whp[2], w3 = whp[3];
    const float4* xr = (const float4*)xdot;  // [t*128 + b]

    // depth-8 prefetch ring keeps the global-load latency off the chain
    float4 buf[8];
#pragma unroll
    for (int p = 0; p < 8; ++p) buf[p] = xr[p * B_DIM + b];

    float c = 0.0f, h = 0.0f;
#pragma unroll 8
    for (int t = 0; t < T_STEPS; ++t) {
        float4 cur = buf[t & 7];
        int tn = t + 8;
        if (tn < T_STEPS) buf[t & 7] = xr[tn * B_DIM + b];

        float q0 = __sinf(fmaf(h, w0, cur.x));
        float q1 = __sinf(fmaf(h, w1, cur.y));
        float q2 = __sinf(fmaf(h, w2, cur.z));
        float q3 = __sinf(fmaf(h, w3, cur.w));
        float f = fsigmoid(q0);
        float i = fsigmoid(q1);
        float g = ftanh_(q2);
        float o = fsigmoid(q3);
        c = fmaf(f, c, i * g);
        h = o * ftanh_(c);
        hseq[t * B_DIM + b] = h;
    }
    cfin[b] = c;
}

// broadcast h over H=256 columns; wave per output row of 64 float4s.
// rows: [0,131072) stacked, [131072,131200) hx, [131200,131328) cx
__global__ __launch_bounds__(256) void k_bcast(const float* __restrict__ hseq,
                                               const float* __restrict__ cfin,
                                               float4* __restrict__ out) {
    const int wave = blockIdx.x * (blockDim.x >> 6) + (threadIdx.x >> 6);
    const int lane = threadIdx.x & 63;
    const int NR = T_STEPS * B_DIM;
    if (wave >= NR + 2 * B_DIM) return;
    float v;
    if (wave < NR)               v = hseq[wave];
    else if (wave < NR + B_DIM)  v = hseq[(T_STEPS - 1) * B_DIM + (wave - NR)];
    else                         v = cfin[wave - NR - B_DIM];
    out[(size_t)wave * 64 + lane] = make_float4(v, v, v, v);
}

extern "C" void kernel_launch(void* const* d_in, const int* in_sizes, int n_in,
                              void* d_out, int out_size, void* d_ws, size_t ws_size,
                              hipStream_t stream) {
    const float* x = (const float*)d_in[0];   // (1024,128,256) f32
    const float* W = (const float*)d_in[1];   // (4,512) f32
    const float* b = (const float*)d_in[2];   // (4,) f32
    // d_in[3] = qw — mathematically inert (sin is invariant to RX then H)

    float* out = (float*)d_out;

    // scratch layout: small stuff in ws, big xdot stashed in d_out's head
    // (consumed by k_scan before k_bcast overwrites all of d_out)
    float* wsf  = (float*)d_ws;
    float* whp  = wsf;                           // 4 floats
    float* hseq = wsf + 16;                      // 131072 floats
    float* cfin = wsf + 16 + T_STEPS * B_DIM;    // 128 floats
    float* xdot = out;                           // 2,097,152 floats (8 MB)

    k_prep<<<1, 256, 0, stream>>>(W, whp);
    k_xdot<<<2048, 256, 0, stream>>>(x, W, b, xdot);
    k_scan<<<1, 128, 0, stream>>>(xdot, whp, hseq, cfin);

    const int rows = T_STEPS * B_DIM + 2 * B_DIM;          // 131328
    k_bcast<<<(rows + 3) / 4, 256, 0, stream>>>(hseq, cfin, (float4*)out);
}

// Round 2
// 369.935 us; speedup vs baseline: 1.0413x; 1.0413x over previous
//
#include <hip/hip_runtime.h>

#define T_STEPS 1024
#define B_DIM   128
#define D_DIM   256
#define H_DIM   256
#define DH      512   // D + H

__device__ __forceinline__ float wave_sum(float v) {
#pragma unroll
    for (int off = 32; off > 0; off >>= 1) v += __shfl_xor(v, off, 64);
    return v;
}

// sigmoid(q) for |q|<=1 (q = sin(...)): Taylor deg-5, err <= 2.2e-4. FMA-only.
__device__ __forceinline__ float sig_poly(float q) {
    float t = q * q;
    float p = fmaf(t, 1.0f / 480.0f, -1.0f / 48.0f);
    p = fmaf(t, p, 0.25f);
    return fmaf(q, p, 0.5f);
}

// tanh(x) Pade(5,4): x(x^4+105x^2+945)/(15x^4+420x^2+945); err<1e-4 for |x|<=2.3.
// |c| provably <= 2.08 (fixed point of f*c+i*g with f,i<=0.731, g<=0.762).
__device__ __forceinline__ float tanh_pade(float x) {
    float t = x * x;
    float n = fmaf(t, t + 105.0f, 945.0f);
    float d = fmaf(t, fmaf(t, 15.0f, 420.0f), 945.0f);
    return x * n * __builtin_amdgcn_rcpf(d);
}

// xdot[row][k] = x[row,:] . W[k,:256] + b[k]   — wave per row, grid-stride
__global__ __launch_bounds__(256) void k_xdot(const float* __restrict__ x,
                                              const float* __restrict__ W,
                                              const float* __restrict__ bias,
                                              float* __restrict__ xdot) {
    const int lane = threadIdx.x & 63;
    const int wid = blockIdx.x * (blockDim.x >> 6) + (threadIdx.x >> 6);
    const int nw = (gridDim.x * blockDim.x) >> 6;
    const int nrows = T_STEPS * B_DIM;

    float4 wk0 = ((const float4*)(W + 0 * DH))[lane];
    float4 wk1 = ((const float4*)(W + 1 * DH))[lane];
    float4 wk2 = ((const float4*)(W + 2 * DH))[lane];
    float4 wk3 = ((const float4*)(W + 3 * DH))[lane];
    const float b0 = bias[0], b1 = bias[1], b2 = bias[2], b3 = bias[3];

    const float4* xv4 = (const float4*)x;  // 64 float4 per row

    int row = wid;
    if (row >= nrows) return;
    float4 xv = xv4[row * 64 + lane];
    for (; row < nrows; row += nw) {
        float4 cur = xv;
        int nrow = row + nw;
        if (nrow < nrows) xv = xv4[nrow * 64 + lane];  // prefetch next row

        float p0 = fmaf(cur.x, wk0.x, fmaf(cur.y, wk0.y, fmaf(cur.z, wk0.z, cur.w * wk0.w)));
        float p1 = fmaf(cur.x, wk1.x, fmaf(cur.y, wk1.y, fmaf(cur.z, wk1.z, cur.w * wk1.w)));
        float p2 = fmaf(cur.x, wk2.x, fmaf(cur.y, wk2.y, fmaf(cur.z, wk2.z, cur.w * wk2.w)));
        float p3 = fmaf(cur.x, wk3.x, fmaf(cur.y, wk3.y, fmaf(cur.z, wk3.z, cur.w * wk3.w)));
        p0 = wave_sum(p0);
        p1 = wave_sum(p1);
        p2 = wave_sum(p2);
        p3 = wave_sum(p3);
        if (lane == 0) {
            float4 r;
            r.x = p0 + b0; r.y = p1 + b1; r.z = p2 + b2; r.w = p3 + b3;
            ((float4*)xdot)[row] = r;
        }
    }
}

// sequential scan: 128 independent chains. k_prep folded into the preamble.
__global__ __launch_bounds__(128) void k_scan(const float* __restrict__ xdot,
                                              const float* __restrict__ W,
                                              float* __restrict__ hseq,
                                              float* __restrict__ cfin) {
    const int b = threadIdx.x;  // 0..127
    __shared__ float s_whp[4];
    {   // whp[k] = sum_h W[k, 256+h]; threads (k = b>>5, j = b&31) each sum 8
        int k = b >> 5, j = b & 31;
        const float4* wr = (const float4*)(W + k * DH + D_DIM + j * 8);
        float4 v0 = wr[0], v1 = wr[1];
        float s = (v0.x + v0.y) + (v0.z + v0.w) + (v1.x + v1.y) + (v1.z + v1.w);
#pragma unroll
        for (int off = 16; off > 0; off >>= 1) s += __shfl_xor(s, off, 32);
        if (j == 0) s_whp[k] = s;
    }
    __syncthreads();
    const float w0 = s_whp[0], w1 = s_whp[1], w2 = s_whp[2], w3 = s_whp[3];
    const float4* xr = (const float4*)xdot;  // [t*128 + b]

    // depth-16 prefetch ring: 16 outstanding loads cover ~1100 cyc of latency
    float4 buf[16];
#pragma unroll
    for (int p = 0; p < 16; ++p) buf[p] = xr[p * B_DIM + b];

    float c = 0.0f, h = 0.0f;
#pragma unroll 16
    for (int t = 0; t < T_STEPS; ++t) {
        float4 cur = buf[t & 15];
        int tn = t + 16;
        if (tn < T_STEPS) buf[t & 15] = xr[tn * B_DIM + b];

        float q0 = __sinf(fmaf(h, w0, cur.x));
        float q1 = __sinf(fmaf(h, w1, cur.y));
        float q2 = __sinf(fmaf(h, w2, cur.z));
        float q3 = __sinf(fmaf(h, w3, cur.w));
        float f = sig_poly(q0);
        float i = sig_poly(q1);
        float g = tanh_pade(q2);
        float o = sig_poly(q3);
        c = fmaf(f, c, i * g);
        h = o * tanh_pade(c);
        hseq[t * B_DIM + b] = h;
    }
    cfin[b] = c;
}

// broadcast h over H=256 columns; wave per output row of 64 float4s.
// rows: [0,131072) stacked, [131072,131200) hx, [131200,131328) cx
__global__ __launch_bounds__(256) void k_bcast(const float* __restrict__ hseq,
                                               const float* __restrict__ cfin,
                                               float4* __restrict__ out) {
    const int wave = blockIdx.x * (blockDim.x >> 6) + (threadIdx.x >> 6);
    const int lane = threadIdx.x & 63;
    const int NR = T_STEPS * B_DIM;
    if (wave >= NR + 2 * B_DIM) return;
    float v;
    if (wave < NR)               v = hseq[wave];
    else if (wave < NR + B_DIM)  v = hseq[(T_STEPS - 1) * B_DIM + (wave - NR)];
    else                         v = cfin[wave - NR - B_DIM];
    out[(size_t)wave * 64 + lane] = make_float4(v, v, v, v);
}

extern "C" void kernel_launch(void* const* d_in, const int* in_sizes, int n_in,
                              void* d_out, int out_size, void* d_ws, size_t ws_size,
                              hipStream_t stream) {
    const float* x = (const float*)d_in[0];   // (1024,128,256) f32
    const float* W = (const float*)d_in[1];   // (4,512) f32
    const float* b = (const float*)d_in[2];   // (4,) f32
    // d_in[3] = qw — mathematically inert (sin invariant under RX then H)

    float* out = (float*)d_out;

    float* wsf  = (float*)d_ws;
    float* hseq = wsf + 16;                      // 131072 floats
    float* cfin = wsf + 16 + T_STEPS * B_DIM;    // 128 floats
    float* xdot = out;                           // 8 MB scratch in d_out head

    k_xdot<<<2048, 256, 0, stream>>>(x, W, b, xdot);
    k_scan<<<1, 128, 0, stream>>>(xdot, W, hseq, cfin);

    const int rows = T_STEPS * B_DIM + 2 * B_DIM;          // 131328
    k_bcast<<<(rows + 3) / 4, 256, 0, stream>>>(hseq, cfin, (float4*)out);
}

// Round 3
// 340.254 us; speedup vs baseline: 1.1322x; 1.0872x over previous
//
#include <hip/hip_runtime.h>

#define T_STEPS 1024
#define B_DIM   128
#define D_DIM   256
#define H_DIM   256
#define DH      512   // D + H

__device__ __forceinline__ float wave_sum(float v) {
#pragma unroll
    for (int off = 32; off > 0; off >>= 1) v += __shfl_xor(v, off, 64);
    return v;
}

// sigmoid(q) for |q|<=1 (q = sin(...)): Taylor deg-5, err <= 2.2e-4. FMA-only.
__device__ __forceinline__ float sig_poly(float q) {
    float t = q * q;
    float p = fmaf(t, 1.0f / 480.0f, -1.0f / 48.0f);
    p = fmaf(t, p, 0.25f);
    return fmaf(q, p, 0.5f);
}

// tanh(x) Pade(5,4): x(x^4+105x^2+945)/(15x^4+420x^2+945); err<1e-4 for |x|<=2.3.
// |c| provably <= 2.08 (fixed point of f*c+i*g with f,i<=0.731, g<=0.762).
__device__ __forceinline__ float tanh_pade(float x) {
    float t = x * x;
    float n = fmaf(t, t + 105.0f, 945.0f);
    float d = fmaf(t, fmaf(t, 15.0f, 420.0f), 945.0f);
    return x * n * __builtin_amdgcn_rcpf(d);
}

// xdot[row][k] = x[row,:] . W[k,:256] + b[k]   — wave per row, grid-stride
__global__ __launch_bounds__(256) void k_xdot(const float* __restrict__ x,
                                              const float* __restrict__ W,
                                              const float* __restrict__ bias,
                                              float* __restrict__ xdot) {
    const int lane = threadIdx.x & 63;
    const int wid = blockIdx.x * (blockDim.x >> 6) + (threadIdx.x >> 6);
    const int nw = (gridDim.x * blockDim.x) >> 6;
    const int nrows = T_STEPS * B_DIM;

    float4 wk0 = ((const float4*)(W + 0 * DH))[lane];
    float4 wk1 = ((const float4*)(W + 1 * DH))[lane];
    float4 wk2 = ((const float4*)(W + 2 * DH))[lane];
    float4 wk3 = ((const float4*)(W + 3 * DH))[lane];
    const float b0 = bias[0], b1 = bias[1], b2 = bias[2], b3 = bias[3];

    const float4* xv4 = (const float4*)x;  // 64 float4 per row

    int row = wid;
    if (row >= nrows) return;
    float4 xv = xv4[row * 64 + lane];
    for (; row < nrows; row += nw) {
        float4 cur = xv;
        int nrow = row + nw;
        if (nrow < nrows) xv = xv4[nrow * 64 + lane];  // prefetch next row

        float p0 = fmaf(cur.x, wk0.x, fmaf(cur.y, wk0.y, fmaf(cur.z, wk0.z, cur.w * wk0.w)));
        float p1 = fmaf(cur.x, wk1.x, fmaf(cur.y, wk1.y, fmaf(cur.z, wk1.z, cur.w * wk1.w)));
        float p2 = fmaf(cur.x, wk2.x, fmaf(cur.y, wk2.y, fmaf(cur.z, wk2.z, cur.w * wk2.w)));
        float p3 = fmaf(cur.x, wk3.x, fmaf(cur.y, wk3.y, fmaf(cur.z, wk3.z, cur.w * wk3.w)));
        p0 = wave_sum(p0);
        p1 = wave_sum(p1);
        p2 = wave_sum(p2);
        p3 = wave_sum(p3);
        if (lane == 0) {
            float4 r;
            r.x = p0 + b0; r.y = p1 + b1; r.z = p2 + b2; r.w = p3 + b3;
            ((float4*)xdot)[row] = r;
        }
    }
}

// sequential scan: 128 independent chains. Prefetch ring kept in REGISTERS:
// inner loop fully unrolled with constant indices so SROA promotes buf[].
// NOTE: prefetch reads up to 16 rows past T_STEPS*B_DIM — caller guarantees
// xdot has >= (T_STEPS+16)*B_DIM float4 of backing store (it's in d_out).
__global__ __launch_bounds__(128) void k_scan(const float* __restrict__ xdot,
                                              const float* __restrict__ W,
                                              float* __restrict__ hseq,
                                              float* __restrict__ cfin) {
    const int b = threadIdx.x;  // 0..127
    __shared__ float s_whp[4];
    {   // whp[k] = sum_h W[k, 256+h]; threads (k = b>>5, j = b&31) each sum 8
        int k = b >> 5, j = b & 31;
        const float4* wr = (const float4*)(W + k * DH + D_DIM + j * 8);
        float4 v0 = wr[0], v1 = wr[1];
        float s = (v0.x + v0.y) + (v0.z + v0.w) + (v1.x + v1.y) + (v1.z + v1.w);
#pragma unroll
        for (int off = 16; off > 0; off >>= 1) s += __shfl_xor(s, off, 32);
        if (j == 0) s_whp[k] = s;
    }
    __syncthreads();
    const float w0 = s_whp[0], w1 = s_whp[1], w2 = s_whp[2], w3 = s_whp[3];
    const float4* xr = (const float4*)xdot;  // [t*128 + b]

    float4 buf[16];
#pragma unroll
    for (int p = 0; p < 16; ++p) buf[p] = xr[p * B_DIM + b];

    float c = 0.0f, h = 0.0f;
    float* hout = hseq + b;
    for (int tb = 0; tb < T_STEPS; tb += 16) {
#pragma unroll
        for (int j = 0; j < 16; ++j) {          // j is compile-time constant
            float4 cur = buf[j];
            buf[j] = xr[(tb + 16 + j) * B_DIM + b];   // 16 steps ahead (padded)

            float q0 = __sinf(fmaf(h, w0, cur.x));
            float q1 = __sinf(fmaf(h, w1, cur.y));
            float q2 = __sinf(fmaf(h, w2, cur.z));
            float q3 = __sinf(fmaf(h, w3, cur.w));
            float f = sig_poly(q0);
            float i = sig_poly(q1);
            float g = tanh_pade(q2);
            float o = sig_poly(q3);
            c = fmaf(f, c, i * g);
            h = o * tanh_pade(c);
            hout[(tb + j) * B_DIM] = h;
        }
    }
    cfin[b] = c;
}

// broadcast h over H=256 columns; wave per output row of 64 float4s.
// rows: [0,131072) stacked, [131072,131200) hx, [131200,131328) cx
__global__ __launch_bounds__(256) void k_bcast(const float* __restrict__ hseq,
                                               const float* __restrict__ cfin,
                                               float4* __restrict__ out) {
    const int wave = blockIdx.x * (blockDim.x >> 6) + (threadIdx.x >> 6);
    const int lane = threadIdx.x & 63;
    const int NR = T_STEPS * B_DIM;
    if (wave >= NR + 2 * B_DIM) return;
    float v;
    if (wave < NR)               v = hseq[wave];
    else if (wave < NR + B_DIM)  v = hseq[(T_STEPS - 1) * B_DIM + (wave - NR)];
    else                         v = cfin[wave - NR - B_DIM];
    out[(size_t)wave * 64 + lane] = make_float4(v, v, v, v);
}

extern "C" void kernel_launch(void* const* d_in, const int* in_sizes, int n_in,
                              void* d_out, int out_size, void* d_ws, size_t ws_size,
                              hipStream_t stream) {
    const float* x = (const float*)d_in[0];   // (1024,128,256) f32
    const float* W = (const float*)d_in[1];   // (4,512) f32
    const float* b = (const float*)d_in[2];   // (4,) f32
    // d_in[3] = qw — mathematically inert (sin invariant under RX then H)

    float* out = (float*)d_out;

    float* wsf  = (float*)d_ws;
    float* hseq = wsf + 16;                      // 131072 floats
    float* cfin = wsf + 16 + T_STEPS * B_DIM;    // 128 floats
    float* xdot = out;  // 8.5 MB scratch in d_out head (incl. 16-row pad);
                        // d_out is 134 MB and fully overwritten by k_bcast.

    k_xdot<<<2048, 256, 0, stream>>>(x, W, b, xdot);
    k_scan<<<1, 128, 0, stream>>>(xdot, W, hseq, cfin);

    const int rows = T_STEPS * B_DIM + 2 * B_DIM;          // 131328
    k_bcast<<<(rows + 3) / 4, 256, 0, stream>>>(hseq, cfin, (float4*)out);
}